// Round 10
// baseline (101.448 us; speedup 1.0000x reference)
//
#include <hip/hip_runtime.h>
#include <hip/hip_bf16.h>

#define SEQ 4096
#define CDIM 512
#define NHEAD 8
#define HDIM 64
#define KVB 64
#define NSPLIT 2
#define TILES_PER_SPLIT (SEQ / KVB / NSPLIT)   // 32

typedef __attribute__((ext_vector_type(8))) short bf16x8;
typedef __attribute__((ext_vector_type(4))) float f32x4;
typedef __attribute__((ext_vector_type(16))) float f32x16;

__device__ __forceinline__ short f2b(float f) {
  union { float f; unsigned u; } v; v.f = f;
  unsigned u = v.u;
  unsigned r = u + 0x7fffu + ((u >> 16) & 1u);
  return (short)(r >> 16);
}
__device__ __forceinline__ float b2f(short s) {
  union { unsigned u; float f; } v; v.u = ((unsigned)(unsigned short)s) << 16;
  return v.f;
}
__device__ __forceinline__ unsigned pk2(float a, float b) {
  union { __hip_bfloat162 h; unsigned u; } z;
  z.h = __float22bfloat162_rn(make_float2(a, b));
  return z.u;
}

// ---- prep: fp32->bf16 convert of x (blocks 0..2047) + 4 weight transposes ----
__global__ __launch_bounds__(256) void prep_kernel(
    const float* __restrict__ x,
    const float* __restrict__ Wq, const float* __restrict__ Wk,
    const float* __restrict__ Wv, const float* __restrict__ Wo,
    short* __restrict__ xb,
    short* __restrict__ Wqt, short* __restrict__ Wkt,
    short* __restrict__ Wvt, short* __restrict__ Wot) {
  __shared__ short tile[32][33];
  int b = blockIdx.x, tid = threadIdx.x;
  if (b < 2048) {
    int i = (b * 256 + tid) * 4;
    float4 v = *(const float4*)(x + i);
    short4 o;
    o.x = f2b(v.x); o.y = f2b(v.y); o.z = f2b(v.z); o.w = f2b(v.w);
    *(short4*)(xb + i) = o;
    return;
  }
  int t = b - 2048;
  int mat = t >> 8; t &= 255;
  const float* W = mat == 0 ? Wq : mat == 1 ? Wk : mat == 2 ? Wv : Wo;
  short* Wt = mat == 0 ? Wqt : mat == 1 ? Wkt : mat == 2 ? Wvt : Wot;
  int n0 = (t & 15) * 32, k0 = (t >> 4) * 32;
  int tx = tid & 31, ty = tid >> 5;  // 32 x 8
  for (int i = 0; i < 32; i += 8)
    tile[ty + i][tx] = f2b(W[(size_t)(k0 + ty + i) * CDIM + n0 + tx]);
  __syncthreads();
  for (int i = 0; i < 32; i += 8)
    Wt[(size_t)(n0 + ty + i) * CDIM + k0 + tx] = tile[tx][ty + i];
}

// ---- fused QKV GEMM (128x64 tiles): z=0 Qb, z=1 Kb (bf16 [M][N]); z=2 Vtb ([N][M]) ----
__global__ __launch_bounds__(256) void qkv128_kernel(
    const short* __restrict__ A,
    const short* __restrict__ Wqt, const short* __restrict__ Wkt, const short* __restrict__ Wvt,
    const float* __restrict__ bq, const float* __restrict__ bk, const float* __restrict__ bv,
    short* __restrict__ Qb, short* __restrict__ Kb, short* __restrict__ Vtb) {
  __shared__ __align__(16) short As[128 * 64];
  __shared__ __align__(16) short Bs[64 * 64];
  const int z = blockIdx.z;
  const short* Bt = z == 0 ? Wqt : z == 1 ? Wkt : Wvt;
  const float* bias = z == 0 ? bq : z == 1 ? bk : bv;
  const int m0 = blockIdx.x * 128, n0 = blockIdx.y * 64;
  f32x16 acc[2] = {};
  const int tid = threadIdx.x;
  const int wid = tid >> 6, lane = tid & 63, l31 = lane & 31, hi = lane >> 5;
  const int wr = wid >> 1, wc = wid & 1;
  for (int kt = 0; kt < CDIM; kt += 64) {
    __syncthreads();
#pragma unroll
    for (int i = 0; i < 4; ++i) {
      int idx = i * 256 + tid, row = idx >> 3, seg = idx & 7;
      int sc = (seg ^ (row & 7)) * 8;
      __builtin_amdgcn_global_load_lds(
          (const __attribute__((address_space(1))) void*)(A + (size_t)(m0 + row) * CDIM + kt + sc),
          (__attribute__((address_space(3))) void*)(As + idx * 8), 16, 0, 0);
    }
#pragma unroll
    for (int i = 0; i < 2; ++i) {
      int idx = i * 256 + tid, row = idx >> 3, seg = idx & 7;
      int sc = (seg ^ (row & 7)) * 8;
      __builtin_amdgcn_global_load_lds(
          (const __attribute__((address_space(1))) void*)(Bt + (size_t)(n0 + row) * CDIM + kt + sc),
          (__attribute__((address_space(3))) void*)(Bs + idx * 8), 16, 0, 0);
    }
    __syncthreads();
#pragma unroll
    for (int ks = 0; ks < 4; ++ks) {
      int brow = wc * 32 + l31;
      bf16x8 bfr = *(const bf16x8*)(Bs + brow * 64 + ((ks * 16 + hi * 8) ^ ((brow & 7) * 8)));
#pragma unroll
      for (int ai = 0; ai < 2; ++ai) {
        int arow = wr * 64 + ai * 32 + l31;
        bf16x8 afr = *(const bf16x8*)(As + arow * 64 + ((ks * 16 + hi * 8) ^ ((arow & 7) * 8)));
        acc[ai] = __builtin_amdgcn_mfma_f32_32x32x16_bf16(afr, bfr, acc[ai], 0, 0, 0);
      }
    }
  }
  const int ncol = n0 + wc * 32 + l31;
  const float bn = bias[ncol];
  if (z != 2) {
    short* D = z == 0 ? Qb : Kb;
#pragma unroll
    for (int ai = 0; ai < 2; ++ai)
#pragma unroll
      for (int r = 0; r < 16; ++r) {
        int m = m0 + wr * 64 + ai * 32 + (r & 3) + 8 * (r >> 2) + 4 * hi;
        D[(size_t)m * CDIM + ncol] = f2b(acc[ai][r] + bn);
      }
  } else {
#pragma unroll
    for (int ai = 0; ai < 2; ++ai)
#pragma unroll
      for (int r = 0; r < 16; ++r) {
        int m = m0 + wr * 64 + ai * 32 + (r & 3) + 8 * (r >> 2) + 4 * hi;
        Vtb[(size_t)ncol * SEQ + m] = f2b(acc[ai][r] + bn);
      }
  }
}

// ---- output projection GEMM (128x64 tiles) with FUSED split-combine:
// A-tile staged via registers as (p0+p1)*rinv -> bf16 -> swizzled ds_write. ----
__global__ __launch_bounds__(256) void out128_kernel(
    const short* __restrict__ p0, const short* __restrict__ p1,
    const float* __restrict__ lpart,     // [2][NHEAD][SEQ]
    const short* __restrict__ Bt, const float* __restrict__ bias,
    float* __restrict__ out) {
  __shared__ __align__(16) short As[128 * 64];
  __shared__ __align__(16) short Bs[64 * 64];
  const int m0 = blockIdx.x * 128, n0 = blockIdx.y * 64;
  f32x16 acc[2] = {};
  const int tid = threadIdx.x;
  const int wid = tid >> 6, lane = tid & 63, l31 = lane & 31, hi = lane >> 5;
  const int wr = wid >> 1, wc = wid & 1;
  for (int kt = 0; kt < CDIM; kt += 64) {
    __syncthreads();
    // A: fused combine (reg-staged)
#pragma unroll
    for (int i = 0; i < 4; ++i) {
      int idx = i * 256 + tid, row = idx >> 3, seg = idx & 7;
      int q = m0 + row, col = kt + seg * 8, h = col >> 6;
      float rinv = 1.f / (lpart[(size_t)h * SEQ + q] + lpart[(size_t)(NHEAD + h) * SEQ + q]);
      bf16x8 a0 = *(const bf16x8*)(p0 + (size_t)q * CDIM + col);
      bf16x8 a1 = *(const bf16x8*)(p1 + (size_t)q * CDIM + col);
      short ov[8];
#pragma unroll
      for (int e = 0; e < 8; ++e) ov[e] = f2b((b2f(a0[e]) + b2f(a1[e])) * rinv);
      *(bf16x8*)(As + row * 64 + ((seg * 8) ^ ((row & 7) * 8))) = *(bf16x8*)ov;
    }
    // B via glds
#pragma unroll
    for (int i = 0; i < 2; ++i) {
      int idx = i * 256 + tid, row = idx >> 3, seg = idx & 7;
      int sc = (seg ^ (row & 7)) * 8;
      __builtin_amdgcn_global_load_lds(
          (const __attribute__((address_space(1))) void*)(Bt + (size_t)(n0 + row) * CDIM + kt + sc),
          (__attribute__((address_space(3))) void*)(Bs + idx * 8), 16, 0, 0);
    }
    __syncthreads();
#pragma unroll
    for (int ks = 0; ks < 4; ++ks) {
      int brow = wc * 32 + l31;
      bf16x8 bfr = *(const bf16x8*)(Bs + brow * 64 + ((ks * 16 + hi * 8) ^ ((brow & 7) * 8)));
#pragma unroll
      for (int ai = 0; ai < 2; ++ai) {
        int arow = wr * 64 + ai * 32 + l31;
        bf16x8 afr = *(const bf16x8*)(As + arow * 64 + ((ks * 16 + hi * 8) ^ ((arow & 7) * 8)));
        acc[ai] = __builtin_amdgcn_mfma_f32_32x32x16_bf16(afr, bfr, acc[ai], 0, 0, 0);
      }
    }
  }
  const int ncol = n0 + wc * 32 + l31;
  const float bn = bias[ncol];
#pragma unroll
  for (int ai = 0; ai < 2; ++ai)
#pragma unroll
    for (int r = 0; r < 16; ++r) {
      int m = m0 + wr * 64 + ai * 32 + (r & 3) + 8 * (r >> 2) + 4 * hi;
      out[(size_t)m * CDIM + ncol] = acc[ai][r] + bn;
    }
}

// ---- flash attention partials (NSPLIT=2, 32 tiles/block), 1-tile-ahead pipeline ----
__global__ __launch_bounds__(512, 4) void attn_kernel(
    const short* __restrict__ Qb,   // [SEQ][CDIM] bf16
    const short* __restrict__ Kb,   // [SEQ][CDIM] bf16
    const short* __restrict__ Vtb,  // [CDIM][SEQ] bf16 (d-major)
    short* __restrict__ Op0, short* __restrict__ Op1,
    float* __restrict__ lpart) {    // [NSPLIT][NHEAD][SEQ]
  __shared__ __align__(16) char arena[49152];   // K 3x8KB + V 3x8KB; epi: bufA[4][64][33] f32
  __shared__ float lzp[4][32];
  short* KsB = (short*)arena;                   // KsB + b*4096
  short* VsB = (short*)(arena + 24576);         // VsB + b*4096
  const int bid = blockIdx.x;
  const int h = bid & 7;                 // head ~ XCD
  const int rest = bid >> 3;
  const int split = rest & 1;
  const int q0 = (rest >> 1) * 128;
  const int kvbase = split * (TILES_PER_SPLIT * KVB);
  const int tid = threadIdx.x;
  const int wid = tid >> 6, lane = tid & 63;
  const int l31 = lane & 31, hi = lane >> 5;
  const int rh = wid >> 1, kq = wid & 1;
  const float scale2 = 0.06375872274f;   // (1/sqrt(512)) * log2(e)

  short* Opart = split == 0 ? Op0 : Op1;

  // Q in B-frag layout (n=q=lane&31, k-slices of d), pre-scaled
  bf16x8 qf[4];
  {
    int qrow = q0 + rh * 32 + l31;
#pragma unroll
    for (int kst = 0; kst < 4; ++kst) {
      bf16x8 q = *(const bf16x8*)(Qb + (size_t)qrow * CDIM + h * 64 + kst * 16 + hi * 8);
#pragma unroll
      for (int i = 0; i < 8; ++i) q[i] = f2b(b2f(q[i]) * scale2);
      qf[kst] = q;
    }
  }

  // glds staging pointers, strength-reduced: advance by constant per stage
  const int srow = tid >> 3;                       // 0..63 (K: kv row; V: d row)
  const int scol8 = 8 * ((tid & 7) ^ (srow & 7));  // inverse-swizzled source col
  const short* kstage = Kb + (size_t)(kvbase + srow) * CDIM + h * 64 + scol8;
  const short* vstage = Vtb + (size_t)(h * 64 + srow) * SEQ + kvbase + scol8;
  auto stage = [&](short* sK, short* sV) {
    __builtin_amdgcn_global_load_lds(
        (const __attribute__((address_space(1))) void*)kstage,
        (__attribute__((address_space(3))) void*)(sK + tid * 8), 16, 0, 0);
    __builtin_amdgcn_global_load_lds(
        (const __attribute__((address_space(1))) void*)vstage,
        (__attribute__((address_space(3))) void*)(sV + tid * 8), 16, 0, 0);
    kstage += KVB * CDIM;
    vstage += KVB;
  };

  f32x16 osum[2] = {};   // dm=0,1 : O^T[d = dm*32 + frag][q]
  float lsum = 0.f;
  unsigned w[8];         // carried P (bf16x2 pairs) for the PV of the previous tile

  auto softmax = [&](f32x16& s) {
    float ls0 = 0.f, ls1 = 0.f;
#pragma unroll
    for (int m = 0; m < 8; ++m) {
      float p0 = __builtin_amdgcn_exp2f(s[2 * m]);
      float p1 = __builtin_amdgcn_exp2f(s[2 * m + 1]);
      ls0 += p0; ls1 += p1;
      w[m] = pk2(p0, p1);
    }
    lsum += ls0 + ls1;
  };

  auto mk_pf = [&](unsigned* u0, unsigned* u1) {
#if __has_builtin(__builtin_amdgcn_permlane32_swap)
    auto a0 = __builtin_amdgcn_permlane32_swap(w[0], w[2], false, false);
    auto a1 = __builtin_amdgcn_permlane32_swap(w[1], w[3], false, false);
    auto a2 = __builtin_amdgcn_permlane32_swap(w[4], w[6], false, false);
    auto a3 = __builtin_amdgcn_permlane32_swap(w[5], w[7], false, false);
    u0[0] = a0[0]; u0[1] = a1[0]; u0[2] = a0[1]; u0[3] = a1[1];
    u1[0] = a2[0]; u1[1] = a3[0]; u1[2] = a2[1]; u1[3] = a3[1];
#else
    unsigned t0 = hi ? w[0] : w[2], t1 = hi ? w[1] : w[3];
    unsigned t2 = hi ? w[4] : w[6], t3 = hi ? w[5] : w[7];
    unsigned r0 = __shfl_xor(t0, 32), r1 = __shfl_xor(t1, 32);
    unsigned r2 = __shfl_xor(t2, 32), r3 = __shfl_xor(t3, 32);
    u0[0] = hi ? r0 : w[0]; u0[1] = hi ? r1 : w[1];
    u0[2] = hi ? w[2] : r0; u0[3] = hi ? w[3] : r1;
    u1[0] = hi ? r2 : w[4]; u1[1] = hi ? r3 : w[5];
    u1[2] = hi ? w[6] : r2; u1[3] = hi ? w[7] : r3;
#endif
  };

  auto phase = [&](const short* vbuf, const short* kbuf, short* sK, short* sV, bool do_st) {
    if (do_st) stage(sK, sV);
    union { unsigned u[4]; bf16x8 v; } pf0, pf1;
    mk_pf(pf0.u, pf1.u);
    f32x16 s = {};
    __builtin_amdgcn_s_setprio(1);
#pragma unroll
    for (int kst = 0; kst < 4; ++kst) {
      int row = kq * 32 + l31;
      bf16x8 kf = *(const bf16x8*)(kbuf + row * 64 + ((kst * 16 + hi * 8) ^ ((row & 7) * 8)));
      s = __builtin_amdgcn_mfma_f32_32x32x16_bf16(kf, qf[kst], s, 0, 0, 0);
    }
#pragma unroll
    for (int dm = 0; dm < 2; ++dm) {
      int vrow = dm * 32 + l31;
      bf16x8 vf0 = *(const bf16x8*)(vbuf + vrow * 64 + ((kq * 32 + hi * 8) ^ ((vrow & 7) * 8)));
      osum[dm] = __builtin_amdgcn_mfma_f32_32x32x16_bf16(vf0, pf0.v, osum[dm], 0, 0, 0);
      bf16x8 vf1 = *(const bf16x8*)(vbuf + vrow * 64 + ((kq * 32 + 16 + hi * 8) ^ ((vrow & 7) * 8)));
      osum[dm] = __builtin_amdgcn_mfma_f32_32x32x16_bf16(vf1, pf1.v, osum[dm], 0, 0, 0);
    }
    __builtin_amdgcn_s_setprio(0);
    softmax(s);
    __syncthreads();
  };

  // prologue: tiles 0 and 1
  stage(KsB, VsB);
  __syncthreads();
  stage(KsB + 4096, VsB + 4096);
  {
    f32x16 s = {};
#pragma unroll
    for (int kst = 0; kst < 4; ++kst) {
      int row = kq * 32 + l31;
      bf16x8 kf = *(const bf16x8*)(KsB + row * 64 + ((kst * 16 + hi * 8) ^ ((row & 7) * 8)));
      s = __builtin_amdgcn_mfma_f32_32x32x16_bf16(kf, qf[kst], s, 0, 0, 0);
    }
    softmax(s);
  }
  __syncthreads();

  // steady state: phases 0..29 (30 = 10 groups x 3, constant buffer addresses)
  for (int t = 0; t + 3 < TILES_PER_SPLIT; t += 3) {
    phase(VsB,        KsB + 4096, KsB + 8192, VsB + 8192, true);
    phase(VsB + 4096, KsB + 8192, KsB,        VsB,        true);
    phase(VsB + 8192, KsB,        KsB + 4096, VsB + 4096, true);
  }
  // phase 30: PV(tile 30, buf 0), QK(tile 31, buf 1), no stage
  phase(VsB, KsB + 4096, KsB, VsB, false);

  // final PV: tile 31 lives in buf 31%3 = 1... careful: phase(t) reads vbuf=t%3.
  // Phase 30 consumed V of tile 30 (buf 0); tile 31's K/V are in buf 31%3 = 1.
  {
    union { unsigned u[4]; bf16x8 v; } pf0, pf1;
    mk_pf(pf0.u, pf1.u);
    const short* vb = VsB + 4096;
#pragma unroll
    for (int dm = 0; dm < 2; ++dm) {
      int vrow = dm * 32 + l31;
      bf16x8 vf0 = *(const bf16x8*)(vb + vrow * 64 + ((kq * 32 + hi * 8) ^ ((vrow & 7) * 8)));
      osum[dm] = __builtin_amdgcn_mfma_f32_32x32x16_bf16(vf0, pf0.v, osum[dm], 0, 0, 0);
      bf16x8 vf1 = *(const bf16x8*)(vb + vrow * 64 + ((kq * 32 + 16 + hi * 8) ^ ((vrow & 7) * 8)));
      osum[dm] = __builtin_amdgcn_mfma_f32_32x32x16_bf16(vf1, pf1.v, osum[dm], 0, 0, 0);
    }
  }

  lsum += __shfl_xor(lsum, 32);

  __syncthreads();
  float* bufA = (float*)arena;              // [4 rh][64 d][33 q]
#define OD(dm, r) ((dm) * 32 + ((r) & 3) + 8 * ((r) >> 2) + 4 * hi)
#define OADDR(dm, r) (rh * 2112 + OD(dm, r) * 33 + l31)
  if (kq == 1) {
    if (hi == 0) lzp[rh][l31] = lsum;
#pragma unroll
    for (int dm = 0; dm < 2; ++dm)
#pragma unroll
      for (int r = 0; r < 16; ++r) bufA[OADDR(dm, r)] = osum[dm][r];
  }
  __syncthreads();
  if (kq == 0) {
#pragma unroll
    for (int dm = 0; dm < 2; ++dm)
#pragma unroll
      for (int r = 0; r < 16; ++r) {
        float v = osum[dm][r] + bufA[OADDR(dm, r)];
        bufA[OADDR(dm, r)] = v;
      }
    float lt = lsum + lzp[rh][l31];
    if (hi == 0)
      lpart[(size_t)(split * NHEAD + h) * SEQ + q0 + rh * 32 + l31] = lt;
  }
  __syncthreads();
#undef OD
#undef OADDR

  {
    int q_ = tid >> 2;             // 0..127
    int dc = (tid & 3) * 16;
    int qr = q_ >> 5, ql = q_ & 31;
    short ov[16];
#pragma unroll
    for (int i = 0; i < 16; ++i)
      ov[i] = f2b(bufA[qr * 2112 + (dc + i) * 33 + ql]);
    *(bf16x8*)(Opart + (size_t)(q0 + q_) * CDIM + h * 64 + dc) = *(bf16x8*)(ov);
    *(bf16x8*)(Opart + (size_t)(q0 + q_) * CDIM + h * 64 + dc + 8) = *(bf16x8*)(ov + 8);
  }
}

extern "C" void kernel_launch(void* const* d_in, const int* in_sizes, int n_in,
                              void* d_out, int out_size, void* d_ws, size_t ws_size,
                              hipStream_t stream) {
  const float* x  = (const float*)d_in[0];
  const float* Wq = (const float*)d_in[1];
  const float* bq = (const float*)d_in[2];
  const float* Wk = (const float*)d_in[3];
  const float* bk = (const float*)d_in[4];
  const float* Wv = (const float*)d_in[5];
  const float* bv = (const float*)d_in[6];
  const float* Wo = (const float*)d_in[7];
  const float* bo = (const float*)d_in[8];
  float* out = (float*)d_out;

  short* ws = (short*)d_ws;
  size_t off = 0;
  short* xb  = ws + off; off += (size_t)SEQ * CDIM;   // reused as O-partial 0
  short* Wqt = ws + off; off += (size_t)CDIM * CDIM;
  short* Wkt = ws + off; off += (size_t)CDIM * CDIM;
  short* Wvt = ws + off; off += (size_t)CDIM * CDIM;
  short* Wot = ws + off; off += (size_t)CDIM * CDIM;
  short* Qb  = ws + off; off += (size_t)SEQ * CDIM;
  short* Kb  = ws + off; off += (size_t)SEQ * CDIM;
  short* Vtb = ws + off; off += (size_t)CDIM * SEQ;
  short* Op1 = ws + off; off += (size_t)SEQ * CDIM;
  float* lpart = (float*)(ws + off); off += (size_t)NSPLIT * NHEAD * SEQ * 2;
  short* Op0 = xb;   // xb is dead after qkv

  prep_kernel<<<2048 + 4 * 256, 256, 0, stream>>>(x, Wq, Wk, Wv, Wo, xb, Wqt, Wkt, Wvt, Wot);
  qkv128_kernel<<<dim3(SEQ / 128, CDIM / 64, 3), 256, 0, stream>>>(
      xb, Wqt, Wkt, Wvt, bq, bk, bv, Qb, Kb, Vtb);
  attn_kernel<<<(SEQ / 128) * NHEAD * NSPLIT, 512, 0, stream>>>(
      Qb, Kb, Vtb, Op0, Op1, lpart);
  out128_kernel<<<dim3(SEQ / 128, CDIM / 64), 256, 0, stream>>>(
      Op0, Op1, lpart, Wot, bo, out);
}

// Round 11
// 77.540 us; speedup vs baseline: 1.3083x; 1.3083x over previous
//
#include <hip/hip_runtime.h>
#include <hip/hip_bf16.h>

#define SEQ 4096
#define CDIM 512
#define NHEAD 8
#define HDIM 64
#define KVB 64
#define NSPLIT 2
#define TILES_PER_SPLIT (SEQ / KVB / NSPLIT)   // 32

typedef __attribute__((ext_vector_type(8))) short bf16x8;
typedef __attribute__((ext_vector_type(4))) float f32x4;
typedef __attribute__((ext_vector_type(16))) float f32x16;

__device__ __forceinline__ short f2b(float f) {
  union { float f; unsigned u; } v; v.f = f;
  unsigned u = v.u;
  unsigned r = u + 0x7fffu + ((u >> 16) & 1u);
  return (short)(r >> 16);
}
__device__ __forceinline__ float b2f(short s) {
  union { unsigned u; float f; } v; v.u = ((unsigned)(unsigned short)s) << 16;
  return v.f;
}
__device__ __forceinline__ unsigned pk2(float a, float b) {
  union { __hip_bfloat162 h; unsigned u; } z;
  z.h = __float22bfloat162_rn(make_float2(a, b));
  return z.u;
}

// ---- prep: fp32->bf16 convert of x (blocks 0..2047) + 4 weight transposes ----
__global__ __launch_bounds__(256) void prep_kernel(
    const float* __restrict__ x,
    const float* __restrict__ Wq, const float* __restrict__ Wk,
    const float* __restrict__ Wv, const float* __restrict__ Wo,
    short* __restrict__ xb,
    short* __restrict__ Wqt, short* __restrict__ Wkt,
    short* __restrict__ Wvt, short* __restrict__ Wot) {
  __shared__ short tile[32][33];
  int b = blockIdx.x, tid = threadIdx.x;
  if (b < 2048) {
    int i = (b * 256 + tid) * 4;
    float4 v = *(const float4*)(x + i);
    short4 o;
    o.x = f2b(v.x); o.y = f2b(v.y); o.z = f2b(v.z); o.w = f2b(v.w);
    *(short4*)(xb + i) = o;
    return;
  }
  int t = b - 2048;
  int mat = t >> 8; t &= 255;
  const float* W = mat == 0 ? Wq : mat == 1 ? Wk : mat == 2 ? Wv : Wo;
  short* Wt = mat == 0 ? Wqt : mat == 1 ? Wkt : mat == 2 ? Wvt : Wot;
  int n0 = (t & 15) * 32, k0 = (t >> 4) * 32;
  int tx = tid & 31, ty = tid >> 5;  // 32 x 8
  for (int i = 0; i < 32; i += 8)
    tile[ty + i][tx] = f2b(W[(size_t)(k0 + ty + i) * CDIM + n0 + tx]);
  __syncthreads();
  for (int i = 0; i < 32; i += 8)
    Wt[(size_t)(n0 + ty + i) * CDIM + k0 + tx] = tile[tx][ty + i];
}

// ---- fused QKV GEMM (128x64 tiles): z=0 Qb, z=1 Kb (bf16 [M][N]); z=2 Vtb ([N][M]) ----
__global__ __launch_bounds__(256) void qkv128_kernel(
    const short* __restrict__ A,
    const short* __restrict__ Wqt, const short* __restrict__ Wkt, const short* __restrict__ Wvt,
    const float* __restrict__ bq, const float* __restrict__ bk, const float* __restrict__ bv,
    short* __restrict__ Qb, short* __restrict__ Kb, short* __restrict__ Vtb) {
  __shared__ __align__(16) short As[128 * 64];
  __shared__ __align__(16) short Bs[64 * 64];
  const int z = blockIdx.z;
  const short* Bt = z == 0 ? Wqt : z == 1 ? Wkt : Wvt;
  const float* bias = z == 0 ? bq : z == 1 ? bk : bv;
  const int m0 = blockIdx.x * 128, n0 = blockIdx.y * 64;
  f32x16 acc[2] = {};
  const int tid = threadIdx.x;
  const int wid = tid >> 6, lane = tid & 63, l31 = lane & 31, hi = lane >> 5;
  const int wr = wid >> 1, wc = wid & 1;
  for (int kt = 0; kt < CDIM; kt += 64) {
    __syncthreads();
#pragma unroll
    for (int i = 0; i < 4; ++i) {
      int idx = i * 256 + tid, row = idx >> 3, seg = idx & 7;
      int sc = (seg ^ (row & 7)) * 8;
      __builtin_amdgcn_global_load_lds(
          (const __attribute__((address_space(1))) void*)(A + (size_t)(m0 + row) * CDIM + kt + sc),
          (__attribute__((address_space(3))) void*)(As + idx * 8), 16, 0, 0);
    }
#pragma unroll
    for (int i = 0; i < 2; ++i) {
      int idx = i * 256 + tid, row = idx >> 3, seg = idx & 7;
      int sc = (seg ^ (row & 7)) * 8;
      __builtin_amdgcn_global_load_lds(
          (const __attribute__((address_space(1))) void*)(Bt + (size_t)(n0 + row) * CDIM + kt + sc),
          (__attribute__((address_space(3))) void*)(Bs + idx * 8), 16, 0, 0);
    }
    __syncthreads();
#pragma unroll
    for (int ks = 0; ks < 4; ++ks) {
      int brow = wc * 32 + l31;
      bf16x8 bfr = *(const bf16x8*)(Bs + brow * 64 + ((ks * 16 + hi * 8) ^ ((brow & 7) * 8)));
#pragma unroll
      for (int ai = 0; ai < 2; ++ai) {
        int arow = wr * 64 + ai * 32 + l31;
        bf16x8 afr = *(const bf16x8*)(As + arow * 64 + ((ks * 16 + hi * 8) ^ ((arow & 7) * 8)));
        acc[ai] = __builtin_amdgcn_mfma_f32_32x32x16_bf16(afr, bfr, acc[ai], 0, 0, 0);
      }
    }
  }
  const int ncol = n0 + wc * 32 + l31;
  const float bn = bias[ncol];
  if (z != 2) {
    short* D = z == 0 ? Qb : Kb;
#pragma unroll
    for (int ai = 0; ai < 2; ++ai)
#pragma unroll
      for (int r = 0; r < 16; ++r) {
        int m = m0 + wr * 64 + ai * 32 + (r & 3) + 8 * (r >> 2) + 4 * hi;
        D[(size_t)m * CDIM + ncol] = f2b(acc[ai][r] + bn);
      }
  } else {
#pragma unroll
    for (int ai = 0; ai < 2; ++ai)
#pragma unroll
      for (int r = 0; r < 16; ++r) {
        int m = m0 + wr * 64 + ai * 32 + (r & 3) + 8 * (r >> 2) + 4 * hi;
        Vtb[(size_t)ncol * SEQ + m] = f2b(acc[ai][r] + bn);
      }
  }
}

// ---- output projection GEMM (128x64 tiles), glds staging from combined Ab ----
__global__ __launch_bounds__(256) void out128_kernel(
    const short* __restrict__ A, const short* __restrict__ Bt,
    const float* __restrict__ bias, float* __restrict__ out) {
  __shared__ __align__(16) short As[128 * 64];
  __shared__ __align__(16) short Bs[64 * 64];
  const int m0 = blockIdx.x * 128, n0 = blockIdx.y * 64;
  f32x16 acc[2] = {};
  const int tid = threadIdx.x;
  const int wid = tid >> 6, lane = tid & 63, l31 = lane & 31, hi = lane >> 5;
  const int wr = wid >> 1, wc = wid & 1;
  for (int kt = 0; kt < CDIM; kt += 64) {
    __syncthreads();
#pragma unroll
    for (int i = 0; i < 4; ++i) {
      int idx = i * 256 + tid, row = idx >> 3, seg = idx & 7;
      int sc = (seg ^ (row & 7)) * 8;
      __builtin_amdgcn_global_load_lds(
          (const __attribute__((address_space(1))) void*)(A + (size_t)(m0 + row) * CDIM + kt + sc),
          (__attribute__((address_space(3))) void*)(As + idx * 8), 16, 0, 0);
    }
#pragma unroll
    for (int i = 0; i < 2; ++i) {
      int idx = i * 256 + tid, row = idx >> 3, seg = idx & 7;
      int sc = (seg ^ (row & 7)) * 8;
      __builtin_amdgcn_global_load_lds(
          (const __attribute__((address_space(1))) void*)(Bt + (size_t)(n0 + row) * CDIM + kt + sc),
          (__attribute__((address_space(3))) void*)(Bs + idx * 8), 16, 0, 0);
    }
    __syncthreads();
#pragma unroll
    for (int ks = 0; ks < 4; ++ks) {
      int brow = wc * 32 + l31;
      bf16x8 bfr = *(const bf16x8*)(Bs + brow * 64 + ((ks * 16 + hi * 8) ^ ((brow & 7) * 8)));
#pragma unroll
      for (int ai = 0; ai < 2; ++ai) {
        int arow = wr * 64 + ai * 32 + l31;
        bf16x8 afr = *(const bf16x8*)(As + arow * 64 + ((ks * 16 + hi * 8) ^ ((arow & 7) * 8)));
        acc[ai] = __builtin_amdgcn_mfma_f32_32x32x16_bf16(afr, bfr, acc[ai], 0, 0, 0);
      }
    }
  }
  const int ncol = n0 + wc * 32 + l31;
  const float bn = bias[ncol];
#pragma unroll
  for (int ai = 0; ai < 2; ++ai)
#pragma unroll
    for (int r = 0; r < 16; ++r) {
      int m = m0 + wr * 64 + ai * 32 + (r & 3) + 8 * (r >> 2) + 4 * hi;
      out[(size_t)m * CDIM + ncol] = acc[ai][r] + bn;
    }
}

// ---- combine 2 kv-split partials: Ab = (p0 + p1) / (l0 + l1) ----
__global__ __launch_bounds__(256) void combine_kernel(
    const short* __restrict__ p0, const short* __restrict__ p1,
    const float* __restrict__ lpart, short* __restrict__ Ab) {
  int t = blockIdx.x * 256 + threadIdx.x;
  size_t base = (size_t)t * 8;
  int q = (int)(base >> 9), c = (int)(base & 511), h = c >> 6;
  float l = lpart[(size_t)h * SEQ + q] + lpart[(size_t)(NHEAD + h) * SEQ + q];
  float rinv = 1.f / l;
  bf16x8 a0 = *(const bf16x8*)(p0 + base);
  bf16x8 a1 = *(const bf16x8*)(p1 + base);
  short ov[8];
#pragma unroll
  for (int i = 0; i < 8; ++i)
    ov[i] = f2b((b2f(a0[i]) + b2f(a1[i])) * rinv);
  *(bf16x8*)(Ab + base) = *(bf16x8*)(ov);
}

// ---- flash attention partials (NSPLIT=2, 32 tiles/block), 1-tile-ahead pipeline ----
__global__ __launch_bounds__(512, 4) void attn_kernel(
    const short* __restrict__ Qb,   // [SEQ][CDIM] bf16
    const short* __restrict__ Kb,   // [SEQ][CDIM] bf16
    const short* __restrict__ Vtb,  // [CDIM][SEQ] bf16 (d-major)
    short* __restrict__ Op0, short* __restrict__ Op1,
    float* __restrict__ lpart) {    // [NSPLIT][NHEAD][SEQ]
  __shared__ __align__(16) char arena[49152];   // K 3x8KB + V 3x8KB; epi: bufA[4][64][33] f32
  __shared__ float lzp[4][32];
  short* KsB = (short*)arena;                   // KsB + b*4096
  short* VsB = (short*)(arena + 24576);         // VsB + b*4096
  const int bid = blockIdx.x;
  const int h = bid & 7;                 // head ~ XCD
  const int rest = bid >> 3;
  const int split = rest & 1;
  const int q0 = (rest >> 1) * 128;
  const int kvbase = split * (TILES_PER_SPLIT * KVB);
  const int tid = threadIdx.x;
  const int wid = tid >> 6, lane = tid & 63;
  const int l31 = lane & 31, hi = lane >> 5;
  const int rh = wid >> 1, kq = wid & 1;
  const float scale2 = 0.06375872274f;   // (1/sqrt(512)) * log2(e)

  short* Opart = split == 0 ? Op0 : Op1;

  // Q in B-frag layout (n=q=lane&31, k-slices of d), pre-scaled
  bf16x8 qf[4];
  {
    int qrow = q0 + rh * 32 + l31;
#pragma unroll
    for (int kst = 0; kst < 4; ++kst) {
      bf16x8 q = *(const bf16x8*)(Qb + (size_t)qrow * CDIM + h * 64 + kst * 16 + hi * 8);
#pragma unroll
      for (int i = 0; i < 8; ++i) q[i] = f2b(b2f(q[i]) * scale2);
      qf[kst] = q;
    }
  }

  // glds staging pointers, strength-reduced: advance by constant per stage
  const int srow = tid >> 3;                       // 0..63 (K: kv row; V: d row)
  const int scol8 = 8 * ((tid & 7) ^ (srow & 7));  // inverse-swizzled source col
  const short* kstage = Kb + (size_t)(kvbase + srow) * CDIM + h * 64 + scol8;
  const short* vstage = Vtb + (size_t)(h * 64 + srow) * SEQ + kvbase + scol8;
  auto stage = [&](short* sK, short* sV) {
    __builtin_amdgcn_global_load_lds(
        (const __attribute__((address_space(1))) void*)kstage,
        (__attribute__((address_space(3))) void*)(sK + tid * 8), 16, 0, 0);
    __builtin_amdgcn_global_load_lds(
        (const __attribute__((address_space(1))) void*)vstage,
        (__attribute__((address_space(3))) void*)(sV + tid * 8), 16, 0, 0);
    kstage += KVB * CDIM;
    vstage += KVB;
  };

  f32x16 osum[2] = {};   // dm=0,1 : O^T[d = dm*32 + frag][q]
  float lsum = 0.f;
  unsigned w[8];         // carried P (bf16x2 pairs) for the PV of the previous tile

  auto softmax = [&](f32x16& s) {
    float ls0 = 0.f, ls1 = 0.f;
#pragma unroll
    for (int m = 0; m < 8; ++m) {
      float p0 = __builtin_amdgcn_exp2f(s[2 * m]);
      float p1 = __builtin_amdgcn_exp2f(s[2 * m + 1]);
      ls0 += p0; ls1 += p1;
      w[m] = pk2(p0, p1);
    }
    lsum += ls0 + ls1;
  };

  auto mk_pf = [&](unsigned* u0, unsigned* u1) {
#if __has_builtin(__builtin_amdgcn_permlane32_swap)
    auto a0 = __builtin_amdgcn_permlane32_swap(w[0], w[2], false, false);
    auto a1 = __builtin_amdgcn_permlane32_swap(w[1], w[3], false, false);
    auto a2 = __builtin_amdgcn_permlane32_swap(w[4], w[6], false, false);
    auto a3 = __builtin_amdgcn_permlane32_swap(w[5], w[7], false, false);
    u0[0] = a0[0]; u0[1] = a1[0]; u0[2] = a0[1]; u0[3] = a1[1];
    u1[0] = a2[0]; u1[1] = a3[0]; u1[2] = a2[1]; u1[3] = a3[1];
#else
    unsigned t0 = hi ? w[0] : w[2], t1 = hi ? w[1] : w[3];
    unsigned t2 = hi ? w[4] : w[6], t3 = hi ? w[5] : w[7];
    unsigned r0 = __shfl_xor(t0, 32), r1 = __shfl_xor(t1, 32);
    unsigned r2 = __shfl_xor(t2, 32), r3 = __shfl_xor(t3, 32);
    u0[0] = hi ? r0 : w[0]; u0[1] = hi ? r1 : w[1];
    u0[2] = hi ? w[2] : r0; u0[3] = hi ? w[3] : r1;
    u1[0] = hi ? r2 : w[4]; u1[1] = hi ? r3 : w[5];
    u1[2] = hi ? w[6] : r2; u1[3] = hi ? w[7] : r3;
#endif
  };

  auto phase = [&](const short* vbuf, const short* kbuf, short* sK, short* sV, bool do_st) {
    if (do_st) stage(sK, sV);
    union { unsigned u[4]; bf16x8 v; } pf0, pf1;
    mk_pf(pf0.u, pf1.u);
    f32x16 s = {};
    __builtin_amdgcn_s_setprio(1);
#pragma unroll
    for (int kst = 0; kst < 4; ++kst) {
      int row = kq * 32 + l31;
      bf16x8 kf = *(const bf16x8*)(kbuf + row * 64 + ((kst * 16 + hi * 8) ^ ((row & 7) * 8)));
      s = __builtin_amdgcn_mfma_f32_32x32x16_bf16(kf, qf[kst], s, 0, 0, 0);
    }
#pragma unroll
    for (int dm = 0; dm < 2; ++dm) {
      int vrow = dm * 32 + l31;
      bf16x8 vf0 = *(const bf16x8*)(vbuf + vrow * 64 + ((kq * 32 + hi * 8) ^ ((vrow & 7) * 8)));
      osum[dm] = __builtin_amdgcn_mfma_f32_32x32x16_bf16(vf0, pf0.v, osum[dm], 0, 0, 0);
      bf16x8 vf1 = *(const bf16x8*)(vbuf + vrow * 64 + ((kq * 32 + 16 + hi * 8) ^ ((vrow & 7) * 8)));
      osum[dm] = __builtin_amdgcn_mfma_f32_32x32x16_bf16(vf1, pf1.v, osum[dm], 0, 0, 0);
    }
    __builtin_amdgcn_s_setprio(0);
    softmax(s);
    __syncthreads();
  };

  // prologue: tiles 0 and 1
  stage(KsB, VsB);
  __syncthreads();
  stage(KsB + 4096, VsB + 4096);
  {
    f32x16 s = {};
#pragma unroll
    for (int kst = 0; kst < 4; ++kst) {
      int row = kq * 32 + l31;
      bf16x8 kf = *(const bf16x8*)(KsB + row * 64 + ((kst * 16 + hi * 8) ^ ((row & 7) * 8)));
      s = __builtin_amdgcn_mfma_f32_32x32x16_bf16(kf, qf[kst], s, 0, 0, 0);
    }
    softmax(s);
  }
  __syncthreads();

  // steady state: phases 0..29 (10 groups x 3, constant buffer addresses)
  for (int t = 0; t + 3 < TILES_PER_SPLIT; t += 3) {
    phase(VsB,        KsB + 4096, KsB + 8192, VsB + 8192, true);
    phase(VsB + 4096, KsB + 8192, KsB,        VsB,        true);
    phase(VsB + 8192, KsB,        KsB + 4096, VsB + 4096, true);
  }
  // phase 30: PV(tile 30, buf 0), QK(tile 31, buf 1), no stage
  phase(VsB, KsB + 4096, KsB, VsB, false);

  // final PV: tile 31's V is in buf 1
  {
    union { unsigned u[4]; bf16x8 v; } pf0, pf1;
    mk_pf(pf0.u, pf1.u);
    const short* vb = VsB + 4096;
#pragma unroll
    for (int dm = 0; dm < 2; ++dm) {
      int vrow = dm * 32 + l31;
      bf16x8 vf0 = *(const bf16x8*)(vb + vrow * 64 + ((kq * 32 + hi * 8) ^ ((vrow & 7) * 8)));
      osum[dm] = __builtin_amdgcn_mfma_f32_32x32x16_bf16(vf0, pf0.v, osum[dm], 0, 0, 0);
      bf16x8 vf1 = *(const bf16x8*)(vb + vrow * 64 + ((kq * 32 + 16 + hi * 8) ^ ((vrow & 7) * 8)));
      osum[dm] = __builtin_amdgcn_mfma_f32_32x32x16_bf16(vf1, pf1.v, osum[dm], 0, 0, 0);
    }
  }

  lsum += __shfl_xor(lsum, 32);

  __syncthreads();
  float* bufA = (float*)arena;              // [4 rh][64 d][33 q]
#define OD(dm, r) ((dm) * 32 + ((r) & 3) + 8 * ((r) >> 2) + 4 * hi)
#define OADDR(dm, r) (rh * 2112 + OD(dm, r) * 33 + l31)
  if (kq == 1) {
    if (hi == 0) lzp[rh][l31] = lsum;
#pragma unroll
    for (int dm = 0; dm < 2; ++dm)
#pragma unroll
      for (int r = 0; r < 16; ++r) bufA[OADDR(dm, r)] = osum[dm][r];
  }
  __syncthreads();
  if (kq == 0) {
#pragma unroll
    for (int dm = 0; dm < 2; ++dm)
#pragma unroll
      for (int r = 0; r < 16; ++r) {
        float v = osum[dm][r] + bufA[OADDR(dm, r)];
        bufA[OADDR(dm, r)] = v;
      }
    float lt = lsum + lzp[rh][l31];
    if (hi == 0)
      lpart[(size_t)(split * NHEAD + h) * SEQ + q0 + rh * 32 + l31] = lt;
  }
  __syncthreads();
#undef OD
#undef OADDR

  {
    int q_ = tid >> 2;             // 0..127
    int dc = (tid & 3) * 16;
    int qr = q_ >> 5, ql = q_ & 31;
    short ov[16];
#pragma unroll
    for (int i = 0; i < 16; ++i)
      ov[i] = f2b(bufA[qr * 2112 + (dc + i) * 33 + ql]);
    *(bf16x8*)(Opart + (size_t)(q0 + q_) * CDIM + h * 64 + dc) = *(bf16x8*)(ov);
    *(bf16x8*)(Opart + (size_t)(q0 + q_) * CDIM + h * 64 + dc + 8) = *(bf16x8*)(ov + 8);
  }
}

extern "C" void kernel_launch(void* const* d_in, const int* in_sizes, int n_in,
                              void* d_out, int out_size, void* d_ws, size_t ws_size,
                              hipStream_t stream) {
  const float* x  = (const float*)d_in[0];
  const float* Wq = (const float*)d_in[1];
  const float* bq = (const float*)d_in[2];
  const float* Wk = (const float*)d_in[3];
  const float* bk = (const float*)d_in[4];
  const float* Wv = (const float*)d_in[5];
  const float* bv = (const float*)d_in[6];
  const float* Wo = (const float*)d_in[7];
  const float* bo = (const float*)d_in[8];
  float* out = (float*)d_out;

  short* ws = (short*)d_ws;
  size_t off = 0;
  short* xb  = ws + off; off += (size_t)SEQ * CDIM;   // reused as O-partial 0
  short* Wqt = ws + off; off += (size_t)CDIM * CDIM;
  short* Wkt = ws + off; off += (size_t)CDIM * CDIM;
  short* Wvt = ws + off; off += (size_t)CDIM * CDIM;
  short* Wot = ws + off; off += (size_t)CDIM * CDIM;
  short* Qb  = ws + off; off += (size_t)SEQ * CDIM;
  short* Kb  = ws + off; off += (size_t)SEQ * CDIM;
  short* Vtb = ws + off; off += (size_t)CDIM * SEQ;
  short* Ab  = ws + off; off += (size_t)SEQ * CDIM;
  short* Op1 = ws + off; off += (size_t)SEQ * CDIM;
  float* lpart = (float*)(ws + off); off += (size_t)NSPLIT * NHEAD * SEQ * 2;
  short* Op0 = xb;   // xb is dead after qkv

  prep_kernel<<<2048 + 4 * 256, 256, 0, stream>>>(x, Wq, Wk, Wv, Wo, xb, Wqt, Wkt, Wvt, Wot);
  qkv128_kernel<<<dim3(SEQ / 128, CDIM / 64, 3), 256, 0, stream>>>(
      xb, Wqt, Wkt, Wvt, bq, bk, bv, Qb, Kb, Vtb);
  attn_kernel<<<(SEQ / 128) * NHEAD * NSPLIT, 512, 0, stream>>>(
      Qb, Kb, Vtb, Op0, Op1, lpart);
  combine_kernel<<<SEQ * CDIM / 8 / 256, 256, 0, stream>>>(Op0, Op1, lpart, Ab);
  out128_kernel<<<dim3(SEQ / 128, CDIM / 64), 256, 0, stream>>>(Ab, Wot, bo, out);
}